// Round 9
// baseline (280.385 us; speedup 1.0000x reference)
//
#include <hip/hip_runtime.h>
#include <hip/hip_bf16.h>
#include <stdint.h>

// Problem constants (from reference)
#define S_  32
#define P_  48
#define T_  8
#define E_  64
#define H_  64
#define D1_ 512
#define D2_ 1024
#define B_  (S_*P_)        // 1536
#define M_  (S_*P_*P_)     // 73728 rows of the big GEMMs
#define K1_ 576            // T*E + H
#define KE_ 512            // T*E
#define SPP 2304           // P_*P_ rows per scene

typedef __attribute__((ext_vector_type(8))) short  short8;
typedef __attribute__((ext_vector_type(4))) short  short4v;
typedef __attribute__((ext_vector_type(8))) __bf16 bf16x8;
typedef __attribute__((ext_vector_type(4))) float  f32x4;
typedef __attribute__((ext_vector_type(8))) float  f32x8;

// fp32 -> bf16 (round to nearest even), bit carrier = short
__device__ inline short f2bf(float x) {
  union { float f; unsigned u; } v; v.f = x;
  unsigned r = v.u + 0x7FFFu + ((v.u >> 16) & 1u);
  return (short)(r >> 16);
}

// async global->LDS, 16 bytes per lane (wave-uniform LDS base + lane*16; the
// GLOBAL source address is per-lane -> T2 swizzle done by pre-swizzling source)
__device__ inline void async16(const void* g, void* l) {
  __builtin_amdgcn_global_load_lds(
      (const __attribute__((address_space(1))) void*)g,
      (__attribute__((address_space(3))) void*)l, 16, 0, 0);
}

__device__ inline f32x4 mfma16(short8 a, short8 b, f32x4 c) {
  return __builtin_amdgcn_mfma_f32_16x16x32_bf16(
      __builtin_bit_cast(bf16x8, a), __builtin_bit_cast(bf16x8, b), c, 0, 0, 0);
}

#define LGKM0_FENCE() do { \
  asm volatile("s_waitcnt lgkmcnt(0)" ::: "memory"); \
  __builtin_amdgcn_sched_barrier(0); } while (0)

// ---------------------------------------------------------------- K0: weights -> bf16
__global__ __launch_bounds__(256) void k_cvt_w(const float* __restrict__ W1,
                                               const float* __restrict__ W2,
                                               short* __restrict__ W1b,
                                               short* __restrict__ W2b) {
  int idx = blockIdx.x * 256 + threadIdx.x;
  if (idx < D1_ * K1_) W1b[idx] = f2bf(W1[idx]);
  int idx2 = idx - D1_ * K1_;
  if (idx2 >= 0 && idx2 < D2_ * D1_) W2b[idx2] = f2bf(W2[idx2]);
}

// ---------------------------------------------------------------- K0b: oW[p][n] = obs[p] @ Wse^T  (fp32)
__global__ __launch_bounds__(256) void k_oW(const float* __restrict__ traj,
                                            const float* __restrict__ Wse,
                                            float* __restrict__ oW) {
  int bid = blockIdx.x;                 // 1536*2 blocks
  int p = bid >> 1;
  int n = ((bid & 1) << 8) + threadIdx.x;
  float obs[16];
#pragma unroll
  for (int t = 0; t < T_; ++t) {
    obs[2*t]   = traj[(t*B_ + p)*2 + 0];
    obs[2*t+1] = traj[(t*B_ + p)*2 + 1];
  }
  float acc = 0.f;
#pragma unroll
  for (int k = 0; k < 16; ++k) acc += obs[k] * Wse[n*16 + k];
  oW[p*KE_ + n] = acc;
}

// ---------------------------------------------------------------- K2: fused build-X + GEMM1 + relu
// X1 = relu(X @ W1^T + b1) where X[row=(s,i,j)] is built ON THE FLY:
//   n<512 : tw[s,rem,n&1,n>>6] * (oW[bj][n] - oW[bi][n] + bse[n])   (n>>6 == kt!)
//   n>=512: h[bj][n-512]
// BM=128 BN=128 BK=64, 4 waves (2x2), wave 64x64, dbuf 64 KB -> 2 blocks/CU.
// A reg-staged (built) + ds_write_b128; B via global_load_lds.
// Swapped-operand MFMA -> lane holds 4 consecutive OUTPUT COLS -> short4 stores.
__global__ __launch_bounds__(256, 2) void k_gemm1f(const float* __restrict__ oW,
                                                   const float* __restrict__ bse,
                                                   const float* __restrict__ tw,
                                                   const float* __restrict__ h,
                                                   const short* __restrict__ W1b,
                                                   const float* __restrict__ b1,
                                                   short* __restrict__ X1) {
  __shared__ short Abuf[2][128 * 64];
  __shared__ short Bbuf[2][128 * 64];
  int tid = threadIdx.x;
  int wid = tid >> 6, lane = tid & 63;
  // T1: grid 2304 = 8 * 288
  int wgid = (blockIdx.x & 7) * 288 + (blockIdx.x >> 3);
  int tm = wgid >> 2, tn = wgid & 3;
  int brow = tm * 128, bcol = tn * 128;
  int wr = wid >> 1, wc = wid & 1;
  int lr = lane & 15, lhi = lane >> 4;
  int sx = lr & 7;                       // T2 read-side XOR (row&7 == lr&7)

  int s     = brow / SPP;                // one scene per block (2304 = 18*128)
  int rem0  = brow - s * SPP;
  int sbase = s * P_;
  const float* tw16 = tw + (size_t)s * SPP * 16;

  f32x4 acc[4][4];
#pragma unroll
  for (int m = 0; m < 4; ++m)
#pragma unroll
    for (int n = 0; n < 4; ++n) acc[m][n] = (f32x4){0.f, 0.f, 0.f, 0.f};

  // Build A-tile for K-tile kt into Abuf[buf]: per thread 4 granules of 8 bf16.
  auto buildA = [&](int buf, int kt) {
    int k0 = kt * 64;
#pragma unroll
    for (int it = 0; it < 4; ++it) {
      int fg = it * 256 + tid;
      int r = fg >> 3, gs = (fg & 7) ^ (r & 7);
      int rem_r = rem0 + r;
      int jj = rem_r % P_;
      int bj = sbase + jj;
      short8 o;
      if (kt < 8) {
        int n0 = k0 + (gs << 3);
        f32x8 vj = *(const f32x8*)&oW[(size_t)bj * KE_ + n0];
        int ii = rem_r / P_;
        f32x8 vi = *(const f32x8*)&oW[(size_t)(sbase + ii) * KE_ + n0];
        f32x8 vb = *(const f32x8*)&bse[n0];
        float w0 = tw16[rem_r * 16 + kt];
        float w1 = tw16[rem_r * 16 + 8 + kt];
#pragma unroll
        for (int e = 0; e < 8; ++e) {
          float v = (vj[e] - vi[e] + vb[e]) * ((e & 1) ? w1 : w0);
          o[e] = f2bf(v);
        }
      } else {                           // h tail: cols 512..575
        f32x8 vh = *(const f32x8*)&h[(size_t)bj * H_ + (gs << 3)];
#pragma unroll
        for (int e = 0; e < 8; ++e) o[e] = f2bf(vh[e]);
      }
      *(short8*)&Abuf[buf][fg * 8] = o;
    }
  };
  auto stageB = [&](int buf, int k0) {
#pragma unroll
    for (int it = 0; it < 4; ++it) {
      int fg = it * 256 + tid;
      int r = fg >> 3, gs = (fg & 7) ^ (r & 7);
      async16(&W1b[(size_t)(bcol + r) * K1_ + k0 + (gs << 3)], &Bbuf[buf][fg * 8]);
    }
  };
  auto compute = [&](int buf) {
#pragma unroll
    for (int kk = 0; kk < 2; ++kk) {
      int gr = kk * 4 + lhi;
      short8 a[4], b[4];
#pragma unroll
      for (int m = 0; m < 4; ++m)
        a[m] = *(const short8*)&Abuf[buf][(wr*64 + m*16 + lr) * 64 + ((gr ^ sx) << 3)];
#pragma unroll
      for (int n = 0; n < 4; ++n)
        b[n] = *(const short8*)&Bbuf[buf][(wc*64 + n*16 + lr) * 64 + ((gr ^ sx) << 3)];
      __builtin_amdgcn_s_setprio(1);
#pragma unroll
      for (int m = 0; m < 4; ++m)
#pragma unroll
        for (int n = 0; n < 4; ++n)
          acc[m][n] = mfma16(b[n], a[m], acc[m][n]);   // SWAPPED operands
      __builtin_amdgcn_s_setprio(0);
    }
  };

  const int NT = 9;                      // K1_/64
  stageB(0, 0);
  buildA(0, 0);
  __syncthreads();                       // drains vm (B) + lgkm (A writes)
  for (int t = 0; t < NT; ++t) {
    int bf = t & 1;
    if (t + 1 < NT) {
      stageB(bf ^ 1, (t + 1) * 64);      // async issue first
      buildA(bf ^ 1, t + 1);             // loads -> pack -> ds_write (other buf)
    }
    compute(bf);
    __syncthreads();
  }

  // epilogue (swapped layout): lane -> row = brow+wr*64+m*16+lr (fixed per m),
  // cols = bcol+wc*64+n*16+lhi*4 + q (4 consecutive) -> short4 (8B) store.
#pragma unroll
  for (int m = 0; m < 4; ++m) {
    int grow = brow + wr*64 + m*16 + lr;
#pragma unroll
    for (int n = 0; n < 4; ++n) {
      int colbase = bcol + wc*64 + n*16 + lhi*4;
      f32x4 bias = *(const f32x4*)&b1[colbase];
      short4v o;
#pragma unroll
      for (int q = 0; q < 4; ++q) {
        float v = acc[m][n][q] + bias[q];
        v = v > 0.f ? v : 0.f;
        o[q] = f2bf(v);
      }
      *(short4v*)&X1[(size_t)grow * D1_ + colbase] = o;
    }
  }
}

// ---------------------------------------------------------------- K3: GEMM2 + relu + max over j
// (unchanged from R8: 91 us known-good)
// BM=192 (4 j-groups), BN=256, BK=64, 8 waves (2M x 4N), wave tile 96x64.
__global__ __launch_bounds__(512, 2) void k_gemm2(const short* __restrict__ X1,
                                                  const short* __restrict__ W2b,
                                                  const float* __restrict__ b2,
                                                  float* __restrict__ out) {
  __shared__ short Abuf[2][192 * 64];   //  48 KB
  __shared__ short Bbuf[3][256 * 64];   //  96 KB  (total 144 KB)
  int tid = threadIdx.x;
  int wid = tid >> 6, lane = tid & 63;
  int wgid = (blockIdx.x & 7) * 192 + (blockIdx.x >> 3);
  int tm = wgid >> 2, tn = wgid & 3;
  int brow = tm * 192, bcol = tn * 256;
  int wr = wid >> 2, wc = wid & 3;
  int lr = lane & 15, lhi = lane >> 4;
  int sx = lr & 7;

  f32x4 acc[6][4];
#pragma unroll
  for (int m = 0; m < 6; ++m)
#pragma unroll
    for (int n = 0; n < 4; ++n) acc[m][n] = (f32x4){0.f, 0.f, 0.f, 0.f};

  auto stageA = [&](int buf, int k0) {
#pragma unroll
    for (int it = 0; it < 3; ++it) {
      int fg = it * 512 + tid;
      int r = fg >> 3, gs = (fg & 7) ^ (r & 7);
      async16(&X1[(size_t)(brow + r) * D1_ + k0 + (gs << 3)], &Abuf[buf][fg * 8]);
    }
  };
  auto stageBh = [&](int buf, int k0, int half) {
#pragma unroll
    for (int it = 0; it < 2; ++it) {
      int fg = (half * 2 + it) * 512 + tid;
      int r = fg >> 3, gs = (fg & 7) ^ (r & 7);
      async16(&W2b[(size_t)(bcol + r) * D1_ + k0 + (gs << 3)], &Bbuf[buf][fg * 8]);
    }
  };
  auto dsA3 = [&](int buf, int kk, int mb, short8* a) {
    int gr = kk * 4 + lhi;
#pragma unroll
    for (int m = 0; m < 3; ++m)
      a[m] = *(const short8*)&Abuf[buf][(wr*96 + (mb + m)*16 + lr) * 64 + ((gr ^ sx) << 3)];
  };
  auto dsB4 = [&](int buf, int kk, short8* b) {
    int gr = kk * 4 + lhi;
#pragma unroll
    for (int n = 0; n < 4; ++n)
      b[n] = *(const short8*)&Bbuf[buf][(wc*64 + n*16 + lr) * 64 + ((gr ^ sx) << 3)];
  };
  auto mf12 = [&](short8* a, short8* b, int mb) {
    __builtin_amdgcn_s_setprio(1);
#pragma unroll
    for (int m = 0; m < 3; ++m)
#pragma unroll
      for (int n = 0; n < 4; ++n)
        acc[mb + m][n] = mfma16(a[m], b[n], acc[mb + m][n]);
    __builtin_amdgcn_s_setprio(0);
  };

  const int NT = 8;                      // D1_/64
  stageA(0, 0); stageBh(0, 0, 0); stageBh(0, 0, 1);
  stageBh(1, 64, 0); stageBh(1, 64, 1);
  asm volatile("s_waitcnt vmcnt(4)" ::: "memory");
  __builtin_amdgcn_s_barrier();
#pragma unroll
  for (int t = 0; t < NT; ++t) {
    int bA = t & 1, bB = t % 3;
    short8 a0[3], b0[4];
    dsA3(bA, 0, 0, a0); dsB4(bB, 0, b0);
    if (t + 1 < NT) stageA(bA ^ 1, (t + 1) * 64);
    __builtin_amdgcn_s_barrier();
    LGKM0_FENCE();
    mf12(a0, b0, 0);
    __builtin_amdgcn_s_barrier();
    short8 a1[3];
    dsA3(bA, 0, 3, a1);
    if (t + 2 < NT) stageBh((t + 2) % 3, (t + 2) * 64, 0);
    __builtin_amdgcn_s_barrier();
    LGKM0_FENCE();
    mf12(a1, b0, 3);
    __builtin_amdgcn_s_barrier();
    short8 a2[3], b1[4];
    dsA3(bA, 1, 0, a2); dsB4(bB, 1, b1);
    if (t + 2 < NT) stageBh((t + 2) % 3, (t + 2) * 64, 1);
    __builtin_amdgcn_s_barrier();
    LGKM0_FENCE();
    mf12(a2, b1, 0);
    __builtin_amdgcn_s_barrier();
    short8 a3[3];
    dsA3(bA, 1, 3, a3);
    __builtin_amdgcn_s_barrier();
    LGKM0_FENCE();
    mf12(a3, b1, 3);
    if (t + 2 < NT)      { asm volatile("s_waitcnt vmcnt(4)" ::: "memory"); }
    else if (t + 1 < NT) { asm volatile("s_waitcnt vmcnt(0)" ::: "memory"); }
    if (t + 1 < NT) __builtin_amdgcn_s_barrier();
  }

  int gbase = tm * 4 + wr * 2;
#pragma unroll
  for (int n = 0; n < 4; ++n) {
    int gcol = bcol + wc*64 + n*16 + lr;
    float bias = b2[gcol];
    float r0 = 0.f, r1 = 0.f;            // relu floor == identity for max(relu)
#pragma unroll
    for (int m = 0; m < 3; ++m)
#pragma unroll
      for (int q = 0; q < 4; ++q) {
        float v0 = acc[m][n][q] + bias;
        float v1 = acc[m + 3][n][q] + bias;
        if (v0 > r0) r0 = v0;
        if (v1 > r1) r1 = v1;
      }
    r0 = fmaxf(r0, __shfl_xor(r0, 16));
    r0 = fmaxf(r0, __shfl_xor(r0, 32));
    r1 = fmaxf(r1, __shfl_xor(r1, 16));
    r1 = fmaxf(r1, __shfl_xor(r1, 32));
    if (lhi == 0) {
      out[(size_t)gbase       * D2_ + gcol] = r0;
      out[(size_t)(gbase + 1) * D2_ + gcol] = r1;
    }
  }
}

// ----------------------------------------------------------------
extern "C" void kernel_launch(void* const* d_in, const int* in_sizes, int n_in,
                              void* d_out, int out_size, void* d_ws, size_t ws_size,
                              hipStream_t stream) {
  const float* h_states = (const float*)d_in[0];
  const float* traj = (const float*)d_in[3];
  const float* tw   = (const float*)d_in[4];
  const float* Wse  = (const float*)d_in[6];
  const float* bse  = (const float*)d_in[7];
  const float* W1   = (const float*)d_in[8];
  const float* b1   = (const float*)d_in[9];
  const float* W2   = (const float*)d_in[10];
  const float* b2   = (const float*)d_in[11];
  float* out = (float*)d_out;

  char* ws = (char*)d_ws;
  const size_t X1_BYTES  = (size_t)M_ * D1_ * 2;   // 75,497,472
  const size_t W1B_BYTES = (size_t)D1_ * K1_ * 2;  //    589,824
  const size_t W2B_BYTES = (size_t)D2_ * D1_ * 2;  //  1,048,576
  short* X1  = (short*)ws;
  short* W1b = (short*)(ws + X1_BYTES);
  short* W2b = (short*)(ws + X1_BYTES + W1B_BYTES);
  float* oW  = (float*)(ws + X1_BYTES + W1B_BYTES + W2B_BYTES);
  // total ~80.3 MB of ws

  k_cvt_w <<<(D1_*K1_ + D2_*D1_ + 255) / 256, 256, 0, stream>>>(W1, W2, W1b, W2b);
  k_oW    <<<B_ * 2, 256, 0, stream>>>(traj, Wse, oW);
  k_gemm1f<<<(M_ / 128) * (D1_ / 128), 256, 0, stream>>>(oW, bse, tw, h_states,
                                                         W1b, b1, X1);
  k_gemm2 <<<(M_ / 192) * (D2_ / 256), 512, 0, stream>>>(X1, W2b, b2, out);
}

// Round 10
// 260.360 us; speedup vs baseline: 1.0769x; 1.0769x over previous
//
#include <hip/hip_runtime.h>
#include <hip/hip_bf16.h>
#include <stdint.h>

// Problem constants (from reference)
#define S_  32
#define P_  48
#define T_  8
#define E_  64
#define H_  64
#define D1_ 512
#define D2_ 1024
#define B_  (S_*P_)        // 1536
#define M_  (S_*P_*P_)     // 73728 rows of the big GEMMs
#define K1_ 576            // T*E + H
#define KE_ 512            // T*E

typedef __attribute__((ext_vector_type(8))) short  short8;
typedef __attribute__((ext_vector_type(4))) short  short4v;
typedef __attribute__((ext_vector_type(8))) __bf16 bf16x8;
typedef __attribute__((ext_vector_type(4))) float  f32x4;
typedef __attribute__((ext_vector_type(8))) float  f32x8;

// fp32 -> bf16 (round to nearest even), bit carrier = short
__device__ inline short f2bf(float x) {
  union { float f; unsigned u; } v; v.f = x;
  unsigned r = v.u + 0x7FFFu + ((v.u >> 16) & 1u);
  return (short)(r >> 16);
}

// async global->LDS, 16 bytes per lane (wave-uniform LDS base + lane*16; the
// GLOBAL source address is per-lane -> T2 swizzle done by pre-swizzling source)
__device__ inline void async16(const void* g, void* l) {
  __builtin_amdgcn_global_load_lds(
      (const __attribute__((address_space(1))) void*)g,
      (__attribute__((address_space(3))) void*)l, 16, 0, 0);
}

__device__ inline f32x4 mfma16(short8 a, short8 b, f32x4 c) {
  return __builtin_amdgcn_mfma_f32_16x16x32_bf16(
      __builtin_bit_cast(bf16x8, a), __builtin_bit_cast(bf16x8, b), c, 0, 0, 0);
}

// ---------------------------------------------------------------- K0: weights -> bf16
__global__ __launch_bounds__(256) void k_cvt_w(const float* __restrict__ W1,
                                               const float* __restrict__ W2,
                                               short* __restrict__ W1b,
                                               short* __restrict__ W2b) {
  int idx = blockIdx.x * 256 + threadIdx.x;
  if (idx < D1_ * K1_) W1b[idx] = f2bf(W1[idx]);
  int idx2 = idx - D1_ * K1_;
  if (idx2 >= 0 && idx2 < D2_ * D1_) W2b[idx2] = f2bf(W2[idx2]);
}

// ---------------------------------------------------------------- K0b: oW[p][n] = obs[p] @ Wse^T  (fp32)
__global__ __launch_bounds__(256) void k_oW(const float* __restrict__ traj,
                                            const float* __restrict__ Wse,
                                            float* __restrict__ oW) {
  int bid = blockIdx.x;                 // 1536*2 blocks
  int p = bid >> 1;
  int n = ((bid & 1) << 8) + threadIdx.x;
  float obs[16];
#pragma unroll
  for (int t = 0; t < T_; ++t) {
    obs[2*t]   = traj[(t*B_ + p)*2 + 0];
    obs[2*t+1] = traj[(t*B_ + p)*2 + 1];
  }
  float acc = 0.f;
#pragma unroll
  for (int k = 0; k < 16; ++k) acc += obs[k] * Wse[n*16 + k];
  oW[p*KE_ + n] = acc;
}

// ---------------------------------------------------------------- K1: build X (bf16)
// X[row=(s,i,j)][n<512]  = tw[s,rem,n&1,n>>6] * (oW[bj][n] - oW[bi][n] + bse[n])
// X[row][n>=512]         = h[bj][n-512]
__global__ __launch_bounds__(256) void k_build_x(const float* __restrict__ tw,
                                                 const float* __restrict__ h,
                                                 const float* __restrict__ bse,
                                                 const float* __restrict__ oW,
                                                 short* __restrict__ X) {
  int tid = threadIdx.x;
  int wid = tid >> 6, lane = tid & 63;
  int row = blockIdx.x * 4 + wid;
  int s   = row / (P_ * P_);
  int rem = row - s * (P_ * P_);
  int i   = rem / P_;
  int j   = rem - i * P_;
  int bi = s * P_ + i, bj = s * P_ + j;

  const float* twq = tw + (size_t)(s * (P_*P_) + rem) * 16;  // [2][8]
  int t = lane >> 3;
  float w0 = twq[t];
  float w1 = twq[8 + t];

  int n0 = lane * 8;
  f32x8 vj = *(const f32x8*)&oW[(size_t)bj * KE_ + n0];
  f32x8 vi = *(const f32x8*)&oW[(size_t)bi * KE_ + n0];
  f32x8 vb = *(const f32x8*)&bse[n0];
  short8 o;
#pragma unroll
  for (int k = 0; k < 8; ++k) {
    float e = (vj[k] - vi[k] + vb[k]) * ((k & 1) ? w1 : w0);
    o[k] = f2bf(e);
  }
  *(short8*)&X[(size_t)row * K1_ + n0] = o;

  if (lane < 8) {
    f32x8 vh = *(const f32x8*)&h[(size_t)bj * H_ + lane * 8];
    short8 oh;
#pragma unroll
    for (int k = 0; k < 8; ++k) oh[k] = f2bf(vh[k]);
    *(short8*)&X[(size_t)row * K1_ + KE_ + lane * 8] = oh;
  }
}

// ---------------------------------------------------------------- K2: GEMM1 + relu
// X1 = relu(X[73728x576] @ W1b[512x576]^T + b1), bf16 out
// BM=288 BN=256 BK=64, 8 waves (2M x 4N), wave tile 144x64 (9 m-frags).
// Grid 512 = 2.0 CLEAN rounds @ 1 block/CU (136 KB LDS). R4-schedule:
// stage(t+1) early -> compute(t) -> vmcnt(0) -> barrier.
// SWAPPED-operand MFMA -> lane holds 4 consecutive cols -> short4 stores.
__global__ __launch_bounds__(512, 2) void k_gemm1(const short* __restrict__ X,
                                                  const short* __restrict__ W1b,
                                                  const float* __restrict__ b1,
                                                  short* __restrict__ X1) {
  __shared__ short Abuf[2][288 * 64];   //  72 KB
  __shared__ short Bbuf[2][256 * 64];   //  64 KB  (total 136 KB)
  int tid = threadIdx.x;
  int wid = tid >> 6, lane = tid & 63;
  // T1: grid 512 = 8 * 64
  int wgid = (blockIdx.x & 7) * 64 + (blockIdx.x >> 3);
  int tm = wgid >> 1, tn = wgid & 1;
  int brow = tm * 288, bcol = tn * 256;
  int wrm = wid >> 2, wcn = wid & 3;     // 2M x 4N, wave 144x64
  int lr = lane & 15, lhi = lane >> 4;
  int sx = lr & 7;                       // T2 read-side XOR (row&7 == lr&7)

  f32x4 acc[9][4];
#pragma unroll
  for (int m = 0; m < 9; ++m)
#pragma unroll
    for (int n = 0; n < 4; ++n) acc[m][n] = (f32x4){0.f, 0.f, 0.f, 0.f};

  auto stageA = [&](int buf, int k0) {   // 2304 granules: 4 full + half pass
#pragma unroll
    for (int it = 0; it < 4; ++it) {
      int fg = it * 512 + tid;
      int r = fg >> 3, gs = (fg & 7) ^ (r & 7);
      async16(&X[(size_t)(brow + r) * K1_ + k0 + (gs << 3)], &Abuf[buf][fg * 8]);
    }
    if (tid < 256) {
      int fg = 2048 + tid;
      int r = fg >> 3, gs = (fg & 7) ^ (r & 7);
      async16(&X[(size_t)(brow + r) * K1_ + k0 + (gs << 3)], &Abuf[buf][fg * 8]);
    }
  };
  auto stageB = [&](int buf, int k0) {   // 2048 granules
#pragma unroll
    for (int it = 0; it < 4; ++it) {
      int fg = it * 512 + tid;
      int r = fg >> 3, gs = (fg & 7) ^ (r & 7);
      async16(&W1b[(size_t)(bcol + r) * K1_ + k0 + (gs << 3)], &Bbuf[buf][fg * 8]);
    }
  };
  auto compute = [&](int buf) {
#pragma unroll
    for (int kk = 0; kk < 2; ++kk) {
      int gr = kk * 4 + lhi;
      short8 a[9], b[4];
#pragma unroll
      for (int m = 0; m < 9; ++m)
        a[m] = *(const short8*)&Abuf[buf][(wrm*144 + m*16 + lr) * 64 + ((gr ^ sx) << 3)];
#pragma unroll
      for (int n = 0; n < 4; ++n)
        b[n] = *(const short8*)&Bbuf[buf][(wcn*64 + n*16 + lr) * 64 + ((gr ^ sx) << 3)];
      __builtin_amdgcn_s_setprio(1);
#pragma unroll
      for (int m = 0; m < 9; ++m)
#pragma unroll
        for (int n = 0; n < 4; ++n)
          acc[m][n] = mfma16(b[n], a[m], acc[m][n]);   // SWAPPED operands
      __builtin_amdgcn_s_setprio(0);
    }
  };

  const int NT = 9;                      // K1_/64
  stageA(0, 0); stageB(0, 0);
  asm volatile("s_waitcnt vmcnt(0)" ::: "memory");
  __builtin_amdgcn_s_barrier();
  for (int t = 0; t < NT; ++t) {
    int bf = t & 1;
    if (t + 1 < NT) { stageA(bf ^ 1, (t + 1) * 64); stageB(bf ^ 1, (t + 1) * 64); }
    compute(bf);
    asm volatile("s_waitcnt vmcnt(0)" ::: "memory");
    __builtin_amdgcn_s_barrier();
  }

  // epilogue (swapped layout): row = brow+wrm*144+m*16+lr, cols = colbase..+3
#pragma unroll
  for (int m = 0; m < 9; ++m) {
    int grow = brow + wrm*144 + m*16 + lr;
#pragma unroll
    for (int n = 0; n < 4; ++n) {
      int colbase = bcol + wcn*64 + n*16 + lhi*4;
      f32x4 bias = *(const f32x4*)&b1[colbase];
      short4v o;
#pragma unroll
      for (int q = 0; q < 4; ++q) {
        float v = acc[m][n][q] + bias[q];
        v = v > 0.f ? v : 0.f;
        o[q] = f2bf(v);
      }
      *(short4v*)&X1[(size_t)grow * D1_ + colbase] = o;
    }
  }
}

// ---------------------------------------------------------------- K3: GEMM2 + relu + max over j
// BM=288 (6 j-groups), BN=256, BK=64, 8 waves (2M x 4N), wave tile 144x64.
// Grid 1024 = 4.0 CLEAN rounds @ 1 block/CU (136 KB LDS). R4-schedule.
// Wave rows = exactly 3 j-groups (m-triples 0-2/3-5/6-8) -> shfl(16,32) max.
__global__ __launch_bounds__(512, 2) void k_gemm2(const short* __restrict__ X1,
                                                  const short* __restrict__ W2b,
                                                  const float* __restrict__ b2,
                                                  float* __restrict__ out) {
  __shared__ short Abuf[2][288 * 64];   //  72 KB
  __shared__ short Bbuf[2][256 * 64];   //  64 KB  (total 136 KB)
  int tid = threadIdx.x;
  int wid = tid >> 6, lane = tid & 63;
  // T1: grid 1024 = 8 * 128
  int wgid = (blockIdx.x & 7) * 128 + (blockIdx.x >> 3);
  int tm = wgid >> 2, tn = wgid & 3;
  int brow = tm * 288, bcol = tn * 256;
  int wrm = wid >> 2, wcn = wid & 3;
  int lr = lane & 15, lhi = lane >> 4;
  int sx = lr & 7;

  f32x4 acc[9][4];
#pragma unroll
  for (int m = 0; m < 9; ++m)
#pragma unroll
    for (int n = 0; n < 4; ++n) acc[m][n] = (f32x4){0.f, 0.f, 0.f, 0.f};

  auto stageA = [&](int buf, int k0) {
#pragma unroll
    for (int it = 0; it < 4; ++it) {
      int fg = it * 512 + tid;
      int r = fg >> 3, gs = (fg & 7) ^ (r & 7);
      async16(&X1[(size_t)(brow + r) * D1_ + k0 + (gs << 3)], &Abuf[buf][fg * 8]);
    }
    if (tid < 256) {
      int fg = 2048 + tid;
      int r = fg >> 3, gs = (fg & 7) ^ (r & 7);
      async16(&X1[(size_t)(brow + r) * D1_ + k0 + (gs << 3)], &Abuf[buf][fg * 8]);
    }
  };
  auto stageB = [&](int buf, int k0) {
#pragma unroll
    for (int it = 0; it < 4; ++it) {
      int fg = it * 512 + tid;
      int r = fg >> 3, gs = (fg & 7) ^ (r & 7);
      async16(&W2b[(size_t)(bcol + r) * D1_ + k0 + (gs << 3)], &Bbuf[buf][fg * 8]);
    }
  };
  auto compute = [&](int buf) {
#pragma unroll
    for (int kk = 0; kk < 2; ++kk) {
      int gr = kk * 4 + lhi;
      short8 a[9], b[4];
#pragma unroll
      for (int m = 0; m < 9; ++m)
        a[m] = *(const short8*)&Abuf[buf][(wrm*144 + m*16 + lr) * 64 + ((gr ^ sx) << 3)];
#pragma unroll
      for (int n = 0; n < 4; ++n)
        b[n] = *(const short8*)&Bbuf[buf][(wcn*64 + n*16 + lr) * 64 + ((gr ^ sx) << 3)];
      __builtin_amdgcn_s_setprio(1);
#pragma unroll
      for (int m = 0; m < 9; ++m)
#pragma unroll
        for (int n = 0; n < 4; ++n)
          acc[m][n] = mfma16(a[m], b[n], acc[m][n]);   // unswapped: col = lr
      __builtin_amdgcn_s_setprio(0);
    }
  };

  const int NT = 8;                      // D1_/64
  stageA(0, 0); stageB(0, 0);
  asm volatile("s_waitcnt vmcnt(0)" ::: "memory");
  __builtin_amdgcn_s_barrier();
  for (int t = 0; t < NT; ++t) {
    int bf = t & 1;
    if (t + 1 < NT) { stageA(bf ^ 1, (t + 1) * 64); stageB(bf ^ 1, (t + 1) * 64); }
    compute(bf);
    asm volatile("s_waitcnt vmcnt(0)" ::: "memory");
    __builtin_amdgcn_s_barrier();
  }

  // epilogue: 3 j-groups per wave (m 0-2, 3-5, 6-8); per-frag max over q,
  // shfl(16,32) over lhi, combine trio in-register, one store per group.
  int gbase = tm * 6 + wrm * 3;          // out row base (s*48+i index space)
#pragma unroll
  for (int n = 0; n < 4; ++n) {
    int gcol = bcol + wcn*64 + n*16 + lr;
    float bias = b2[gcol];
    float gm[3] = {0.f, 0.f, 0.f};       // relu floor == identity for max(relu)
#pragma unroll
    for (int m = 0; m < 9; ++m) {
      float r = 0.f;
#pragma unroll
      for (int q = 0; q < 4; ++q) {
        float v = acc[m][n][q] + bias;
        if (v > r) r = v;
      }
      int g = m / 3;
      if (r > gm[g]) gm[g] = r;
    }
#pragma unroll
    for (int g = 0; g < 3; ++g) {
      float r = gm[g];
      r = fmaxf(r, __shfl_xor(r, 16));
      r = fmaxf(r, __shfl_xor(r, 32));
      if (lhi == 0) out[(size_t)(gbase + g) * D2_ + gcol] = r;
    }
  }
}

// ----------------------------------------------------------------
extern "C" void kernel_launch(void* const* d_in, const int* in_sizes, int n_in,
                              void* d_out, int out_size, void* d_ws, size_t ws_size,
                              hipStream_t stream) {
  const float* h_states = (const float*)d_in[0];
  const float* traj = (const float*)d_in[3];
  const float* tw   = (const float*)d_in[4];
  const float* Wse  = (const float*)d_in[6];
  const float* bse  = (const float*)d_in[7];
  const float* W1   = (const float*)d_in[8];
  const float* b1   = (const float*)d_in[9];
  const float* W2   = (const float*)d_in[10];
  const float* b2   = (const float*)d_in[11];
  float* out = (float*)d_out;

  char* ws = (char*)d_ws;
  const size_t X_BYTES   = (size_t)M_ * K1_ * 2;   // 84,934,656
  const size_t X1_BYTES  = (size_t)M_ * D1_ * 2;   // 75,497,472
  const size_t W1B_BYTES = (size_t)D1_ * K1_ * 2;  //    589,824
  short* X   = (short*)ws;
  short* X1  = (short*)(ws + X_BYTES);
  short* W1b = (short*)(ws + X_BYTES + X1_BYTES);
  short* W2b = (short*)(ws + X_BYTES + X1_BYTES + W1B_BYTES);
  // oW (3 MB fp32) aliases head of X1: consumed by k_build_x before k_gemm1
  float* oW  = (float*)(ws + X_BYTES);

  k_cvt_w  <<<(D1_*K1_ + D2_*D1_ + 255) / 256, 256, 0, stream>>>(W1, W2, W1b, W2b);
  k_oW     <<<B_ * 2, 256, 0, stream>>>(traj, Wse, oW);
  k_build_x<<<M_ / 4, 256, 0, stream>>>(tw, h_states, bse, oW, X);
  k_gemm1  <<<(M_ / 288) * (D1_ / 256), 512, 0, stream>>>(X, W1b, b1, X1);
  k_gemm2  <<<(M_ / 288) * (D2_ / 256), 512, 0, stream>>>(X1, W2b, b2, out);
}